// Round 1
// baseline (3554.588 us; speedup 1.0000x reference)
//
#include <hip/hip_runtime.h>
#include <math.h>

// GAT layer: N nodes, E edges, FIN=128 in-features, H=8 heads, F=16 per head.
// Pipeline:
//   memset(denom, maxbuf)
//   k_proj : proj = x@W_proj, s_src/s_trg per node, per-head global maxes
//   k_skip : d_out = x@W_skip + bias
//   k_denom: denom[trg,h] += exp(lrelu(s_src[src]+s_trg[trg]) - M)   (atomics)
//   k_agg  : d_out[trg,h,f] += proj[src,h,f] * att                   (atomics)
//   k_elu  : d_out = elu(d_out)

#define HF 128   // H*F
#define FIN 128

__device__ __forceinline__ unsigned int enc_f(float f) {
    unsigned int u = __float_as_uint(f);
    return (u & 0x80000000u) ? ~u : (u | 0x80000000u);
}
__device__ __forceinline__ float dec_f(unsigned int e) {
    return (e & 0x80000000u) ? __uint_as_float(e ^ 0x80000000u) : __uint_as_float(~e);
}

// ---------------- proj GEMM + score halves + per-head max ----------------
// 64 rows/block, 256 threads. Thread (cg=t&31, rg=t>>5) computes rows
// rg*8..rg*8+7 x cols cg*4..cg*4+3. x tile in LDS (32KB), W from global (L1/L2-hot).
__global__ __launch_bounds__(256) void k_proj(
    const float* __restrict__ x, const float* __restrict__ W,
    const float* __restrict__ av_src, const float* __restrict__ av_trg,
    float* __restrict__ proj, float* __restrict__ ssrc, float* __restrict__ strg,
    unsigned int* __restrict__ maxbuf, int N)
{
    __shared__ float xs[64][FIN];
    __shared__ unsigned int smax[16];
    const int t = threadIdx.x;
    const int row0 = blockIdx.x * 64;
    if (t < 16) smax[t] = 0u;

    const int nrows = min(64, N - row0);
    {
        const float4* xg = (const float4*)(x + (size_t)row0 * FIN);
        float4* xs4 = (float4*)&xs[0][0];
        for (int i = t; i < nrows * (FIN / 4); i += 256) xs4[i] = xg[i];
        for (int i = nrows * (FIN / 4) + t; i < 64 * (FIN / 4); i += 256)
            xs4[i] = make_float4(0.f, 0.f, 0.f, 0.f);
    }
    __syncthreads();

    const int cg = t & 31;
    const int rg = t >> 5;
    const int c0 = cg * 4;
    const int r0 = rg * 8;

    float4 acc[8];
#pragma unroll
    for (int r = 0; r < 8; r++) acc[r] = make_float4(0.f, 0.f, 0.f, 0.f);

#pragma unroll 4
    for (int k = 0; k < FIN; k++) {
        const float4 wv = *(const float4*)(W + k * HF + c0);
#pragma unroll
        for (int r = 0; r < 8; r++) {
            const float xv = xs[r0 + r][k];
            acc[r].x += xv * wv.x; acc[r].y += xv * wv.y;
            acc[r].z += xv * wv.z; acc[r].w += xv * wv.w;
        }
    }

    const float4 as = *(const float4*)(av_src + c0);
    const float4 at = *(const float4*)(av_trg + c0);
    const int h = cg >> 2;
    float mx_s = -3e38f, mx_t = -3e38f;
#pragma unroll
    for (int r = 0; r < 8; r++) {
        const int row = row0 + r0 + r;
        const bool valid = row < N;
        if (valid) *(float4*)(proj + (size_t)row * HF + c0) = acc[r];
        float ps = acc[r].x * as.x + acc[r].y * as.y + acc[r].z * as.z + acc[r].w * as.w;
        float pt = acc[r].x * at.x + acc[r].y * at.y + acc[r].z * at.z + acc[r].w * at.w;
        ps += __shfl_xor(ps, 1); ps += __shfl_xor(ps, 2);
        pt += __shfl_xor(pt, 1); pt += __shfl_xor(pt, 2);
        if ((cg & 3) == 0 && valid) {
            ssrc[(size_t)row * 8 + h] = ps;
            strg[(size_t)row * 8 + h] = pt;
            mx_s = fmaxf(mx_s, ps);
            mx_t = fmaxf(mx_t, pt);
        }
    }
    if ((cg & 3) == 0) {
        atomicMax(&smax[h], enc_f(mx_s));
        atomicMax(&smax[8 + h], enc_f(mx_t));
    }
    __syncthreads();
    if (t < 16) atomicMax(&maxbuf[t], smax[t]);
}

// ---------------- skip GEMM + bias -> d_out ----------------
__global__ __launch_bounds__(256) void k_skip(
    const float* __restrict__ x, const float* __restrict__ W,
    const float* __restrict__ bias, float* __restrict__ out, int N)
{
    __shared__ float xs[64][FIN];
    const int t = threadIdx.x;
    const int row0 = blockIdx.x * 64;
    const int nrows = min(64, N - row0);
    {
        const float4* xg = (const float4*)(x + (size_t)row0 * FIN);
        float4* xs4 = (float4*)&xs[0][0];
        for (int i = t; i < nrows * (FIN / 4); i += 256) xs4[i] = xg[i];
    }
    __syncthreads();

    const int cg = t & 31;
    const int rg = t >> 5;
    const int c0 = cg * 4;
    const int r0 = rg * 8;

    float4 acc[8];
#pragma unroll
    for (int r = 0; r < 8; r++) acc[r] = make_float4(0.f, 0.f, 0.f, 0.f);

#pragma unroll 4
    for (int k = 0; k < FIN; k++) {
        const float4 wv = *(const float4*)(W + k * HF + c0);
#pragma unroll
        for (int r = 0; r < 8; r++) {
            const float xv = xs[r0 + r][k];
            acc[r].x += xv * wv.x; acc[r].y += xv * wv.y;
            acc[r].z += xv * wv.z; acc[r].w += xv * wv.w;
        }
    }
    const float4 bv = *(const float4*)(bias + c0);
#pragma unroll
    for (int r = 0; r < 8; r++) {
        const int row = row0 + r0 + r;
        if (row < N) {
            float4 v = acc[r];
            v.x += bv.x; v.y += bv.y; v.z += bv.z; v.w += bv.w;
            *(float4*)(out + (size_t)row * HF + c0) = v;
        }
    }
}

// ---------------- per-edge exp-score -> denom atomics ----------------
__global__ __launch_bounds__(256) void k_denom(
    const int* __restrict__ ei, const float* __restrict__ ssrc,
    const float* __restrict__ strg, const unsigned int* __restrict__ maxbuf,
    float* __restrict__ denom, int E)
{
    __shared__ float Msh;
    if (threadIdx.x == 0) {
        float M = -3e38f;
        for (int h = 0; h < 8; h++) M = fmaxf(M, dec_f(maxbuf[h]) + dec_f(maxbuf[8 + h]));
        Msh = M;
    }
    __syncthreads();
    const float M = Msh;
    const int e = blockIdx.x * 256 + threadIdx.x;
    if (e >= E) return;
    const int s  = ei[e];
    const int tg = ei[E + e];
    const float4 a0 = *(const float4*)(ssrc + (size_t)s * 8);
    const float4 a1 = *(const float4*)(ssrc + (size_t)s * 8 + 4);
    const float4 b0 = *(const float4*)(strg + (size_t)tg * 8);
    const float4 b1 = *(const float4*)(strg + (size_t)tg * 8 + 4);
    float sc[8] = { a0.x + b0.x, a0.y + b0.y, a0.z + b0.z, a0.w + b0.w,
                    a1.x + b1.x, a1.y + b1.y, a1.z + b1.z, a1.w + b1.w };
#pragma unroll
    for (int h = 0; h < 8; h++) {
        float v = sc[h];
        v = v > 0.f ? v : 0.2f * v;
        atomicAdd(denom + (size_t)tg * 8 + h, __expf(v - M));
    }
}

// ---------------- aggregation: 32 lanes per edge, 4 feats each ----------------
__global__ __launch_bounds__(256) void k_agg(
    const int* __restrict__ ei, const float* __restrict__ ssrc,
    const float* __restrict__ strg, const float* __restrict__ denom,
    const float* __restrict__ proj, const unsigned int* __restrict__ maxbuf,
    float* __restrict__ out, int E)
{
    __shared__ float Msh;
    if (threadIdx.x == 0) {
        float M = -3e38f;
        for (int h = 0; h < 8; h++) M = fmaxf(M, dec_f(maxbuf[h]) + dec_f(maxbuf[8 + h]));
        Msh = M;
    }
    __syncthreads();
    const float M = Msh;
    const long long gt = (long long)blockIdx.x * 256 + threadIdx.x;
    const int e = (int)(gt >> 5);
    if (e >= E) return;
    const int l = (int)(gt & 31);
    const int s  = ei[e];
    const int tg = ei[E + e];
    const int h = l >> 2;
    const float ss = ssrc[(size_t)s * 8 + h];
    const float st = strg[(size_t)tg * 8 + h];
    float v = ss + st;
    v = v > 0.f ? v : 0.2f * v;
    const float p = __expf(v - M);
    const float d = denom[(size_t)tg * 8 + h];
    const float att = p / (d + 1e-16f);
    const float4 pv = *(const float4*)(proj + (size_t)s * HF + l * 4);
    float* o = out + (size_t)tg * HF + l * 4;
    atomicAdd(o + 0, pv.x * att);
    atomicAdd(o + 1, pv.y * att);
    atomicAdd(o + 2, pv.z * att);
    atomicAdd(o + 3, pv.w * att);
}

// ---------------- ELU ----------------
__global__ __launch_bounds__(256) void k_elu(float* __restrict__ out, int n4)
{
    const int i = blockIdx.x * 256 + threadIdx.x;
    if (i >= n4) return;
    float4 v = ((float4*)out)[i];
    v.x = v.x > 0.f ? v.x : expm1f(v.x);
    v.y = v.y > 0.f ? v.y : expm1f(v.y);
    v.z = v.z > 0.f ? v.z : expm1f(v.z);
    v.w = v.w > 0.f ? v.w : expm1f(v.w);
    ((float4*)out)[i] = v;
}

extern "C" void kernel_launch(void* const* d_in, const int* in_sizes, int n_in,
                              void* d_out, int out_size, void* d_ws, size_t ws_size,
                              hipStream_t stream)
{
    const float* x      = (const float*)d_in[0];
    const int*   ei     = (const int*)d_in[1];
    const float* W_proj = (const float*)d_in[2];
    const float* a_src  = (const float*)d_in[3];
    const float* a_trg  = (const float*)d_in[4];
    const float* W_skip = (const float*)d_in[5];
    const float* bias   = (const float*)d_in[6];
    float* out = (float*)d_out;

    const int N = in_sizes[0] / FIN;
    const int E = in_sizes[1] / 2;

    float* proj = (float*)d_ws;                          // N*128 f32
    float* ssrc = proj + (size_t)N * HF;                 // N*8
    float* strg = ssrc + (size_t)N * 8;                  // N*8
    float* denom = strg + (size_t)N * 8;                 // N*8
    unsigned int* maxbuf = (unsigned int*)(denom + (size_t)N * 8);  // 16 u32

    // zero denom + maxbuf (ws is poisoned 0xAA before every timed launch)
    hipMemsetAsync(denom, 0, (size_t)N * 8 * sizeof(float) + 16 * sizeof(unsigned int), stream);

    const int gemm_blocks = (N + 63) / 64;
    k_proj<<<gemm_blocks, 256, 0, stream>>>(x, W_proj, a_src, a_trg, proj, ssrc, strg, maxbuf, N);
    k_skip<<<gemm_blocks, 256, 0, stream>>>(x, W_skip, bias, out, N);
    k_denom<<<(E + 255) / 256, 256, 0, stream>>>(ei, ssrc, strg, maxbuf, denom, E);

    const long long agg_threads = (long long)E * 32;
    const int agg_blocks = (int)((agg_threads + 255) / 256);
    k_agg<<<agg_blocks, 256, 0, stream>>>(ei, ssrc, strg, denom, proj, maxbuf, out, E);

    const int n4 = out_size / 4;
    k_elu<<<(n4 + 255) / 256, 256, 0, stream>>>(out, n4);
}

// Round 2
// 692.780 us; speedup vs baseline: 5.1309x; 5.1309x over previous
//
#include <hip/hip_runtime.h>
#include <math.h>

// GAT layer: N nodes, E edges, FIN=128 in-features, H=8 heads, F=16 per head.
// Round-2 pipeline (CSR gather, zero f32 scatter-atomics in the hot path):
//   memset(offs, maxbuf)
//   k_gemm2  : proj = x@W_proj (+s_src/s_trg, per-head maxes), out = x@W_skip + bias
//   k_hist   : offs[trg]++                                  (int atomics, L2)
//   k_scan   : exclusive prefix sum over offs (single block)
//   k_scatter: csr_src[offs[trg]++] = src                   (int atomics, L2)
//   k_agg_csr: per-node wave gathers in-edges, accumulates Σp·proj and Σp in
//              registers, writes out = elu(Σp·proj/(Σp+eps) + skip) once.

#define HF 128   // H*F
#define FIN 128

__device__ __forceinline__ unsigned int enc_f(float f) {
    unsigned int u = __float_as_uint(f);
    return (u & 0x80000000u) ? ~u : (u | 0x80000000u);
}
__device__ __forceinline__ float dec_f(unsigned int e) {
    return (e & 0x80000000u) ? __uint_as_float(e ^ 0x80000000u) : __uint_as_float(~e);
}

// ---------------- fused proj+skip GEMM + score halves + per-head max ----------------
// 64 rows/block, 256 threads. Thread (cg=t&31, rg=t>>5) computes rows
// rg*8..rg*8+7 x cols cg*4..cg*4+3 for BOTH weight matrices.
// LDS reads: wave = 2 rg groups -> 2 addresses on the same bank = 2-way = free (m136).
__global__ __launch_bounds__(256) void k_gemm2(
    const float* __restrict__ x,
    const float* __restrict__ Wp, const float* __restrict__ Wk,
    const float* __restrict__ av_src, const float* __restrict__ av_trg,
    const float* __restrict__ bias,
    float* __restrict__ proj, float* __restrict__ out,
    float* __restrict__ ssrc, float* __restrict__ strg,
    unsigned int* __restrict__ maxbuf, int N)
{
    __shared__ float xs[64][FIN];
    __shared__ unsigned int smax[16];
    const int t = threadIdx.x;
    const int row0 = blockIdx.x * 64;
    if (t < 16) smax[t] = 0u;

    const int nrows = min(64, N - row0);
    {
        const float4* xg = (const float4*)(x + (size_t)row0 * FIN);
        float4* xs4 = (float4*)&xs[0][0];
        for (int i = t; i < nrows * (FIN / 4); i += 256) xs4[i] = xg[i];
        for (int i = nrows * (FIN / 4) + t; i < 64 * (FIN / 4); i += 256)
            xs4[i] = make_float4(0.f, 0.f, 0.f, 0.f);
    }
    __syncthreads();

    const int cg = t & 31;
    const int rg = t >> 5;
    const int c0 = cg * 4;
    const int r0 = rg * 8;

    float4 accp[8], acck[8];
#pragma unroll
    for (int r = 0; r < 8; r++) {
        accp[r] = make_float4(0.f, 0.f, 0.f, 0.f);
        acck[r] = make_float4(0.f, 0.f, 0.f, 0.f);
    }

#pragma unroll 2
    for (int k = 0; k < FIN; k++) {
        const float4 wp = *(const float4*)(Wp + k * HF + c0);
        const float4 wk = *(const float4*)(Wk + k * HF + c0);
#pragma unroll
        for (int r = 0; r < 8; r++) {
            const float xv = xs[r0 + r][k];
            accp[r].x += xv * wp.x; accp[r].y += xv * wp.y;
            accp[r].z += xv * wp.z; accp[r].w += xv * wp.w;
            acck[r].x += xv * wk.x; acck[r].y += xv * wk.y;
            acck[r].z += xv * wk.z; acck[r].w += xv * wk.w;
        }
    }

    const float4 as = *(const float4*)(av_src + c0);
    const float4 at = *(const float4*)(av_trg + c0);
    const float4 bv = *(const float4*)(bias + c0);
    const int h = cg >> 2;
    float mx_s = -3e38f, mx_t = -3e38f;
#pragma unroll
    for (int r = 0; r < 8; r++) {
        const int row = row0 + r0 + r;
        const bool valid = row < N;
        if (valid) {
            *(float4*)(proj + (size_t)row * HF + c0) = accp[r];
            float4 v = acck[r];
            v.x += bv.x; v.y += bv.y; v.z += bv.z; v.w += bv.w;
            *(float4*)(out + (size_t)row * HF + c0) = v;
        }
        float ps = accp[r].x * as.x + accp[r].y * as.y + accp[r].z * as.z + accp[r].w * as.w;
        float pt = accp[r].x * at.x + accp[r].y * at.y + accp[r].z * at.z + accp[r].w * at.w;
        ps += __shfl_xor(ps, 1); ps += __shfl_xor(ps, 2);
        pt += __shfl_xor(pt, 1); pt += __shfl_xor(pt, 2);
        if ((cg & 3) == 0 && valid) {
            ssrc[(size_t)row * 8 + h] = ps;
            strg[(size_t)row * 8 + h] = pt;
            mx_s = fmaxf(mx_s, ps);
            mx_t = fmaxf(mx_t, pt);
        }
    }
    if ((cg & 3) == 0) {
        atomicMax(&smax[h], enc_f(mx_s));
        atomicMax(&smax[8 + h], enc_f(mx_t));
    }
    __syncthreads();
    if (t < 16) atomicMax(&maxbuf[t], smax[t]);
}

// ---------------- degree histogram ----------------
__global__ __launch_bounds__(256) void k_hist(
    const int* __restrict__ ei, int* __restrict__ offs, int E)
{
    const int e = blockIdx.x * 256 + threadIdx.x;
    if (e < E) atomicAdd(&offs[ei[E + e]], 1);
}

// ---------------- single-block exclusive scan (in-place) ----------------
__global__ __launch_bounds__(1024) void k_scan(int* __restrict__ offs, int N)
{
    __shared__ int lds[1024];
    const int t = threadIdx.x;
    const int chunk = (N + 1023) >> 10;
    const int b = t * chunk;
    const int e = min(b + chunk, N);
    int sum = 0;
    for (int i = b; i < e; i++) sum += offs[i];
    lds[t] = sum;
    __syncthreads();
    for (int off = 1; off < 1024; off <<= 1) {
        int v = (t >= off) ? lds[t - off] : 0;
        __syncthreads();
        lds[t] += v;
        __syncthreads();
    }
    int run = lds[t] - sum;   // exclusive prefix
    for (int i = b; i < e; i++) { int tmp = offs[i]; offs[i] = run; run += tmp; }
}

// ---------------- scatter edge srcs into CSR ----------------
// After this kernel offs[t] == end of segment t (cursor trick).
__global__ __launch_bounds__(256) void k_scatter(
    const int* __restrict__ ei, int* __restrict__ offs,
    int* __restrict__ csr_src, int E)
{
    const int e = blockIdx.x * 256 + threadIdx.x;
    if (e >= E) return;
    const int s  = ei[e];
    const int tg = ei[E + e];
    const int pos = atomicAdd(&offs[tg], 1);
    csr_src[pos] = s;
}

// ---------------- gather aggregation: one 64-lane wave per target node ----------------
// lane l: head h = l>>3, feature pair f2 = (l&7)*2  ->  out elem t*128 + l*2 (coalesced).
__global__ __launch_bounds__(256) void k_agg_csr(
    const int* __restrict__ offs, const int* __restrict__ csr_src,
    const float* __restrict__ ssrc, const float* __restrict__ strg,
    const float* __restrict__ proj, const unsigned int* __restrict__ maxbuf,
    float* __restrict__ out, int N)
{
    __shared__ float Msh;
    if (threadIdx.x == 0) {
        float M = -3e38f;
        for (int h = 0; h < 8; h++) M = fmaxf(M, dec_f(maxbuf[h]) + dec_f(maxbuf[8 + h]));
        Msh = M;
    }
    __syncthreads();
    const float M = Msh;
    const int wid = threadIdx.x >> 6;
    const int l   = threadIdx.x & 63;
    const int t   = blockIdx.x * 4 + wid;
    if (t >= N) return;
    const int h  = l >> 3;
    const int f2 = (l & 7) * 2;

    const int start = (t == 0) ? 0 : offs[t - 1];
    const int end   = offs[t];
    const float st = strg[(size_t)t * 8 + h];

    float acc0 = 0.f, acc1 = 0.f, den = 0.f;
    int s_next = (start < end) ? csr_src[start] : 0;
    for (int i = start; i < end; i++) {
        const int s = s_next;
        if (i + 1 < end) s_next = csr_src[i + 1];
        float v = ssrc[(size_t)s * 8 + h] + st;
        v = v > 0.f ? v : 0.2f * v;
        const float p = __expf(v - M);
        den += p;
        const float2 pv = *(const float2*)(proj + (size_t)s * HF + h * 16 + f2);
        acc0 += p * pv.x;
        acc1 += p * pv.y;
    }

    const float inv = 1.f / (den + 1e-16f);
    float* o = out + (size_t)t * HF + l * 2;
    const float2 sk = *(const float2*)o;      // skip + bias, written by k_gemm2
    float r0 = acc0 * inv + sk.x;
    float r1 = acc1 * inv + sk.y;
    r0 = r0 > 0.f ? r0 : expm1f(r0);
    r1 = r1 > 0.f ? r1 : expm1f(r1);
    *(float2*)o = make_float2(r0, r1);
}

extern "C" void kernel_launch(void* const* d_in, const int* in_sizes, int n_in,
                              void* d_out, int out_size, void* d_ws, size_t ws_size,
                              hipStream_t stream)
{
    const float* x      = (const float*)d_in[0];
    const int*   ei     = (const int*)d_in[1];
    const float* W_proj = (const float*)d_in[2];
    const float* a_src  = (const float*)d_in[3];
    const float* a_trg  = (const float*)d_in[4];
    const float* W_skip = (const float*)d_in[5];
    const float* bias   = (const float*)d_in[6];
    float* out = (float*)d_out;

    const int N = in_sizes[0] / FIN;
    const int E = in_sizes[1] / 2;

    float* proj = (float*)d_ws;                               // N*128 f32
    float* ssrc = proj + (size_t)N * HF;                      // N*8
    float* strg = ssrc + (size_t)N * 8;                       // N*8
    int*   offs = (int*)(strg + (size_t)N * 8);               // N+1 ints
    unsigned int* maxbuf = (unsigned int*)(offs + (size_t)N + 1);  // 16 u32
    int*   csr_src = (int*)(maxbuf + 16);                     // E ints

    // zero offs + maxbuf (ws is poisoned 0xAA before every timed launch)
    hipMemsetAsync(offs, 0, ((size_t)N + 1 + 16) * sizeof(int), stream);

    const int gemm_blocks = (N + 63) / 64;
    k_gemm2<<<gemm_blocks, 256, 0, stream>>>(x, W_proj, W_skip, a_src, a_trg, bias,
                                             proj, out, ssrc, strg, maxbuf, N);
    k_hist<<<(E + 255) / 256, 256, 0, stream>>>(ei, offs, E);
    k_scan<<<1, 1024, 0, stream>>>(offs, N);
    k_scatter<<<(E + 255) / 256, 256, 0, stream>>>(ei, offs, csr_src, E);
    k_agg_csr<<<(N + 3) / 4, 256, 0, stream>>>(offs, csr_src, ssrc, strg, proj, maxbuf, out, N);
}

// Round 3
// 536.172 us; speedup vs baseline: 6.6296x; 1.2921x over previous
//
#include <hip/hip_runtime.h>
#include <math.h>

// GAT layer: N nodes, E edges, FIN=128 in-features, H=8 heads, F=16 per head.
// Round-3 pipeline (CSR gather + multi-block scan):
//   memset(offs, maxbuf)
//   k_gemm2     : proj = x@W_proj (+s_src/s_trg, maxes), out = x@W_skip + bias
//   k_hist      : offs[trg]++                              (int atomics, L2)
//   k_scan_local/bsum/add : two-level exclusive prefix sum (was 166us single-block)
//   k_scatter   : csr_src[offs[trg]++] = src               (int atomics, L2)
//   k_agg_csr   : per-node wave gathers in-edges, single write of
//                 elu(sum(p*proj)/(sum p + eps) + skip).

#define HF 128   // H*F
#define FIN 128

__device__ __forceinline__ unsigned int enc_f(float f) {
    unsigned int u = __float_as_uint(f);
    return (u & 0x80000000u) ? ~u : (u | 0x80000000u);
}
__device__ __forceinline__ float dec_f(unsigned int e) {
    return (e & 0x80000000u) ? __uint_as_float(e ^ 0x80000000u) : __uint_as_float(~e);
}

// ---------------- fused proj+skip GEMM + score halves + per-head max ----------------
__global__ __launch_bounds__(256) void k_gemm2(
    const float* __restrict__ x,
    const float* __restrict__ Wp, const float* __restrict__ Wk,
    const float* __restrict__ av_src, const float* __restrict__ av_trg,
    const float* __restrict__ bias,
    float* __restrict__ proj, float* __restrict__ out,
    float* __restrict__ ssrc, float* __restrict__ strg,
    unsigned int* __restrict__ maxbuf, int N)
{
    __shared__ float xs[64][FIN];
    __shared__ unsigned int smax[16];
    const int t = threadIdx.x;
    const int row0 = blockIdx.x * 64;
    if (t < 16) smax[t] = 0u;

    const int nrows = min(64, N - row0);
    {
        const float4* xg = (const float4*)(x + (size_t)row0 * FIN);
        float4* xs4 = (float4*)&xs[0][0];
        for (int i = t; i < nrows * (FIN / 4); i += 256) xs4[i] = xg[i];
        for (int i = nrows * (FIN / 4) + t; i < 64 * (FIN / 4); i += 256)
            xs4[i] = make_float4(0.f, 0.f, 0.f, 0.f);
    }
    __syncthreads();

    const int cg = t & 31;
    const int rg = t >> 5;
    const int c0 = cg * 4;
    const int r0 = rg * 8;

    float4 accp[8], acck[8];
#pragma unroll
    for (int r = 0; r < 8; r++) {
        accp[r] = make_float4(0.f, 0.f, 0.f, 0.f);
        acck[r] = make_float4(0.f, 0.f, 0.f, 0.f);
    }

#pragma unroll 2
    for (int k = 0; k < FIN; k++) {
        const float4 wp = *(const float4*)(Wp + k * HF + c0);
        const float4 wk = *(const float4*)(Wk + k * HF + c0);
#pragma unroll
        for (int r = 0; r < 8; r++) {
            const float xv = xs[r0 + r][k];
            accp[r].x += xv * wp.x; accp[r].y += xv * wp.y;
            accp[r].z += xv * wp.z; accp[r].w += xv * wp.w;
            acck[r].x += xv * wk.x; acck[r].y += xv * wk.y;
            acck[r].z += xv * wk.z; acck[r].w += xv * wk.w;
        }
    }

    const float4 as = *(const float4*)(av_src + c0);
    const float4 at = *(const float4*)(av_trg + c0);
    const float4 bv = *(const float4*)(bias + c0);
    const int h = cg >> 2;
    float mx_s = -3e38f, mx_t = -3e38f;
#pragma unroll
    for (int r = 0; r < 8; r++) {
        const int row = row0 + r0 + r;
        const bool valid = row < N;
        if (valid) {
            *(float4*)(proj + (size_t)row * HF + c0) = accp[r];
            float4 v = acck[r];
            v.x += bv.x; v.y += bv.y; v.z += bv.z; v.w += bv.w;
            *(float4*)(out + (size_t)row * HF + c0) = v;
        }
        float ps = accp[r].x * as.x + accp[r].y * as.y + accp[r].z * as.z + accp[r].w * as.w;
        float pt = accp[r].x * at.x + accp[r].y * at.y + accp[r].z * at.z + accp[r].w * at.w;
        ps += __shfl_xor(ps, 1); ps += __shfl_xor(ps, 2);
        pt += __shfl_xor(pt, 1); pt += __shfl_xor(pt, 2);
        if ((cg & 3) == 0 && valid) {
            ssrc[(size_t)row * 8 + h] = ps;
            strg[(size_t)row * 8 + h] = pt;
            mx_s = fmaxf(mx_s, ps);
            mx_t = fmaxf(mx_t, pt);
        }
    }
    if ((cg & 3) == 0) {
        atomicMax(&smax[h], enc_f(mx_s));
        atomicMax(&smax[8 + h], enc_f(mx_t));
    }
    __syncthreads();
    if (t < 16) atomicMax(&maxbuf[t], smax[t]);
}

// ---------------- degree histogram ----------------
__global__ __launch_bounds__(256) void k_hist(
    const int* __restrict__ ei, int* __restrict__ offs, int E)
{
    const int e = blockIdx.x * 256 + threadIdx.x;
    if (e < E) atomicAdd(&offs[ei[E + e]], 1);
}

// ---------------- two-level exclusive scan ----------------
// Level 1: 1024 threads x 4 elems = 4096/block. Block-local exclusive scan,
// block total -> bsums[b].
__global__ __launch_bounds__(1024) void k_scan_local(
    int* __restrict__ offs, int* __restrict__ bsums, int N)
{
    __shared__ int lds[1024];
    const int t = threadIdx.x;
    const int base = blockIdx.x * 4096 + t * 4;
    int4 v = make_int4(0, 0, 0, 0);
    if (base + 3 < N) v = *(const int4*)(offs + base);
    else {
        if (base + 0 < N) v.x = offs[base + 0];
        if (base + 1 < N) v.y = offs[base + 1];
        if (base + 2 < N) v.z = offs[base + 2];
        if (base + 3 < N) v.w = offs[base + 3];
    }
    const int s = v.x + v.y + v.z + v.w;
    lds[t] = s;
    __syncthreads();
    for (int off = 1; off < 1024; off <<= 1) {
        int u = (t >= off) ? lds[t - off] : 0;
        __syncthreads();
        lds[t] += u;
        __syncthreads();
    }
    if (t == 1023) bsums[blockIdx.x] = lds[1023];
    int run = lds[t] - s;          // exclusive prefix of this thread's chunk
    int4 w;
    w.x = run; run += v.x;
    w.y = run; run += v.y;
    w.z = run; run += v.z;
    w.w = run;
    if (base + 3 < N) *(int4*)(offs + base) = w;
    else {
        if (base + 0 < N) offs[base + 0] = w.x;
        if (base + 1 < N) offs[base + 1] = w.y;
        if (base + 2 < N) offs[base + 2] = w.z;
        if (base + 3 < N) offs[base + 3] = w.w;
    }
}

// Level 2: single small block scans block sums (nb <= 256).
__global__ __launch_bounds__(256) void k_scan_bsum(int* __restrict__ bsums, int nb)
{
    __shared__ int lds[256];
    const int t = threadIdx.x;
    const int v = (t < nb) ? bsums[t] : 0;
    lds[t] = v;
    __syncthreads();
    for (int off = 1; off < 256; off <<= 1) {
        int u = (t >= off) ? lds[t - off] : 0;
        __syncthreads();
        lds[t] += u;
        __syncthreads();
    }
    if (t < nb) bsums[t] = lds[t] - v;   // exclusive
}

// Level 3: add scanned block sums back.
__global__ __launch_bounds__(1024) void k_scan_add(
    int* __restrict__ offs, const int* __restrict__ bsums, int N)
{
    const int add = bsums[blockIdx.x];
    if (add == 0) return;
    const int base = blockIdx.x * 4096 + threadIdx.x * 4;
    if (base + 3 < N) {
        int4 v = *(int4*)(offs + base);
        v.x += add; v.y += add; v.z += add; v.w += add;
        *(int4*)(offs + base) = v;
    } else {
        for (int i = 0; i < 4; i++) if (base + i < N) offs[base + i] += add;
    }
}

// ---------------- scatter edge srcs into CSR ----------------
// After this kernel offs[t] == end of segment t (cursor trick).
__global__ __launch_bounds__(256) void k_scatter(
    const int* __restrict__ ei, int* __restrict__ offs,
    int* __restrict__ csr_src, int E)
{
    const int e = blockIdx.x * 256 + threadIdx.x;
    if (e >= E) return;
    const int s  = ei[e];
    const int tg = ei[E + e];
    const int pos = atomicAdd(&offs[tg], 1);
    csr_src[pos] = s;
}

// ---------------- gather aggregation: one 64-lane wave per target node ----------------
// lane l: head h = l>>3, feature pair f2 = (l&7)*2 -> out elem t*128 + l*2 (coalesced).
__global__ __launch_bounds__(256) void k_agg_csr(
    const int* __restrict__ offs, const int* __restrict__ csr_src,
    const float* __restrict__ ssrc, const float* __restrict__ strg,
    const float* __restrict__ proj, const unsigned int* __restrict__ maxbuf,
    float* __restrict__ out, int N)
{
    __shared__ float Msh;
    if (threadIdx.x == 0) {
        float M = -3e38f;
        for (int h = 0; h < 8; h++) M = fmaxf(M, dec_f(maxbuf[h]) + dec_f(maxbuf[8 + h]));
        Msh = M;
    }
    __syncthreads();
    const float M = Msh;
    const int wid = threadIdx.x >> 6;
    const int l   = threadIdx.x & 63;
    const int t   = blockIdx.x * 4 + wid;
    if (t >= N) return;
    const int h  = l >> 3;
    const int f2 = (l & 7) * 2;

    const int start = (t == 0) ? 0 : offs[t - 1];
    const int end   = offs[t];
    const float st = strg[(size_t)t * 8 + h];

    float acc0 = 0.f, acc1 = 0.f, den = 0.f;
    int s_next = (start < end) ? csr_src[start] : 0;
    for (int i = start; i < end; i++) {
        const int s = s_next;
        if (i + 1 < end) s_next = csr_src[i + 1];
        float v = ssrc[(size_t)s * 8 + h] + st;
        v = v > 0.f ? v : 0.2f * v;
        const float p = __expf(v - M);
        den += p;
        const float2 pv = *(const float2*)(proj + (size_t)s * HF + h * 16 + f2);
        acc0 += p * pv.x;
        acc1 += p * pv.y;
    }

    const float inv = 1.f / (den + 1e-16f);
    float* o = out + (size_t)t * HF + l * 2;
    const float2 sk = *(const float2*)o;      // skip + bias, written by k_gemm2
    float r0 = acc0 * inv + sk.x;
    float r1 = acc1 * inv + sk.y;
    r0 = r0 > 0.f ? r0 : expm1f(r0);
    r1 = r1 > 0.f ? r1 : expm1f(r1);
    *(float2*)o = make_float2(r0, r1);
}

extern "C" void kernel_launch(void* const* d_in, const int* in_sizes, int n_in,
                              void* d_out, int out_size, void* d_ws, size_t ws_size,
                              hipStream_t stream)
{
    const float* x      = (const float*)d_in[0];
    const int*   ei     = (const int*)d_in[1];
    const float* W_proj = (const float*)d_in[2];
    const float* a_src  = (const float*)d_in[3];
    const float* a_trg  = (const float*)d_in[4];
    const float* W_skip = (const float*)d_in[5];
    const float* bias   = (const float*)d_in[6];
    float* out = (float*)d_out;

    const int N = in_sizes[0] / FIN;
    const int E = in_sizes[1] / 2;

    float* proj = (float*)d_ws;                               // N*128 f32
    float* ssrc = proj + (size_t)N * HF;                      // N*8
    float* strg = ssrc + (size_t)N * 8;                       // N*8
    int*   offs = (int*)(strg + (size_t)N * 8);               // N+1 ints
    unsigned int* maxbuf = (unsigned int*)(offs + (size_t)N + 1);  // 16 u32
    int*   bsums = (int*)(maxbuf + 16);                       // 256 ints
    int*   csr_src = bsums + 256;                             // E ints

    // zero offs + maxbuf (ws is poisoned 0xAA before every timed launch)
    hipMemsetAsync(offs, 0, ((size_t)N + 1 + 16) * sizeof(int), stream);

    const int gemm_blocks = (N + 63) / 64;
    k_gemm2<<<gemm_blocks, 256, 0, stream>>>(x, W_proj, W_skip, a_src, a_trg, bias,
                                             proj, out, ssrc, strg, maxbuf, N);
    k_hist<<<(E + 255) / 256, 256, 0, stream>>>(ei, offs, E);

    const int scan_blocks = (N + 4095) / 4096;   // 25 for N=100000 (<=256 supported)
    k_scan_local<<<scan_blocks, 1024, 0, stream>>>(offs, bsums, N);
    k_scan_bsum<<<1, 256, 0, stream>>>(bsums, scan_blocks);
    k_scan_add<<<scan_blocks, 1024, 0, stream>>>(offs, bsums, N);

    k_scatter<<<(E + 255) / 256, 256, 0, stream>>>(ei, offs, csr_src, E);
    k_agg_csr<<<(N + 3) / 4, 256, 0, stream>>>(offs, csr_src, ssrc, strg, proj, maxbuf, out, N);
}

// Round 4
// 490.550 us; speedup vs baseline: 7.2461x; 1.0930x over previous
//
#include <hip/hip_runtime.h>
#include <math.h>

// GAT layer: N nodes, E edges, FIN=128 in-features, H=8 heads, F=16 per head.
// Round-4 pipeline (MFMA GEMM + bf16 proj/skip tables + CSR gather):
//   memset(offs, maxbuf)
//   k_prep     : repack Wp||Wk (128x256 f32) into MFMA B-fragment bf16 layout
//   k_gemm_mfma: proj16 = bf16(x@Wp), skip16 = bf16(x@Wk)  [16x16x32 bf16 MFMA]
//   k_scores   : ssrc/strg[N,8] from proj16, per-head global maxes
//   k_hist     : offs[trg]++                       (int atomics, L2)
//   k_scan_*   : two-level exclusive prefix sum
//   k_scatter  : csr_src[offs[trg]++] = src        (int atomics, L2)
//   k_agg_csr  : per-node wave gathers in-edges (bf16 proj), writes
//                out = elu(sum(p*proj)/(sum p+eps) + skip + bias) once, f32.

#define HF 128   // H*F
#define FIN 128

typedef __attribute__((ext_vector_type(8))) short short8;   // 8 bf16 (4 VGPR)
typedef __attribute__((ext_vector_type(4))) float f32x4;    // MFMA acc

__device__ __forceinline__ unsigned int enc_f(float f) {
    unsigned int u = __float_as_uint(f);
    return (u & 0x80000000u) ? ~u : (u | 0x80000000u);
}
__device__ __forceinline__ float dec_f(unsigned int e) {
    return (e & 0x80000000u) ? __uint_as_float(e ^ 0x80000000u) : __uint_as_float(~e);
}
__device__ __forceinline__ unsigned short f2bf(float f) {   // RNE f32->bf16
    unsigned int u = __float_as_uint(f);
    return (unsigned short)((u + 0x7FFFu + ((u >> 16) & 1u)) >> 16);
}
__device__ __forceinline__ float bf_lo(unsigned int u) { return __uint_as_float(u << 16); }
__device__ __forceinline__ float bf_hi(unsigned int u) { return __uint_as_float(u & 0xFFFF0000u); }

// ---------------- W repack into MFMA B-frag layout ----------------
// Frag fi=(ct*4+ks): lane l, elem j  <-  W'[k=ks*32+(l>>4)*8+j][c=ct*16+(l&15)]
// W' = [Wp | Wk] (256 cols). Output: Wb[fi*512 + l*8 + j] bf16.
__global__ __launch_bounds__(256) void k_prep(
    const float* __restrict__ Wp, const float* __restrict__ Wk,
    unsigned short* __restrict__ Wb)
{
    const int ct = blockIdx.x;          // 0..15
    const int t = threadIdx.x;
    const int ks = t >> 6, lane = t & 63;
    const int k0 = ks * 32 + (lane >> 4) * 8;
    const int c  = ct * 16 + (lane & 15);
    const float* W = (c < 128) ? (Wp + c) : (Wk + c - 128);
    unsigned short v[8];
#pragma unroll
    for (int j = 0; j < 8; j++) v[j] = f2bf(W[(k0 + j) * HF]);
    uint4 q;
    q.x = v[0] | ((unsigned int)v[1] << 16);
    q.y = v[2] | ((unsigned int)v[3] << 16);
    q.z = v[4] | ((unsigned int)v[5] << 16);
    q.w = v[6] | ((unsigned int)v[7] << 16);
    *(uint4*)(Wb + ((size_t)(ct * 4 + ks) * 64 + lane) * 8) = q;
}

// ---------------- MFMA GEMM: [64 rows] x [256 cols], K=128 ----------------
// 4 waves/block; wave w owns cols w*64..w*64+63 (waves 0-1 -> proj, 2-3 -> skip).
// x staged to LDS as bf16 with XOR swizzle (byte ^= (row&7)<<4) for
// conflict-free ds_read_b128 A-frag loads.
__global__ __launch_bounds__(256) void k_gemm_mfma(
    const float* __restrict__ x, const unsigned short* __restrict__ Wb,
    unsigned short* __restrict__ proj16, unsigned short* __restrict__ skip16, int N)
{
    __shared__ unsigned short xs[64 * FIN];   // 16 KB bf16, swizzled
    char* xb = (char*)xs;
    const int t = threadIdx.x;
    const int w = t >> 6, lane = t & 63;
    const int row0 = blockIdx.x * 64;

    // B-frags: held in registers for whole kernel (L2-hot after first blocks)
    short8 b[4][4];
    {
        const short8* wb8 = (const short8*)Wb;
#pragma unroll
        for (int nt = 0; nt < 4; nt++)
#pragma unroll
            for (int ks = 0; ks < 4; ks++)
                b[nt][ks] = wb8[(size_t)(w * 16 + nt * 4 + ks) * 64 + lane];
    }

    // stage x tile -> bf16 LDS (swizzled). 2048 float4 chunks, 8 per thread.
    {
        const float4* xg = (const float4*)(x + (size_t)row0 * FIN);
#pragma unroll
        for (int it = 0; it < 8; it++) {
            const int i = t + it * 256;
            const int row = i >> 5, c4 = i & 31;
            float4 v = make_float4(0.f, 0.f, 0.f, 0.f);
            if (row0 + row < N) v = xg[i];
            ushort4 pk;
            pk.x = f2bf(v.x); pk.y = f2bf(v.y); pk.z = f2bf(v.z); pk.w = f2bf(v.w);
            const int byte = (row * 256 + c4 * 8) ^ ((row & 7) << 4);
            *(ushort4*)(xb + byte) = pk;
        }
    }
    __syncthreads();

    f32x4 acc[4][4];
#pragma unroll
    for (int mt = 0; mt < 4; mt++)
#pragma unroll
        for (int nt = 0; nt < 4; nt++)
            acc[mt][nt] = (f32x4){0.f, 0.f, 0.f, 0.f};

#pragma unroll
    for (int ks = 0; ks < 4; ks++) {
        short8 a[4];
#pragma unroll
        for (int mt = 0; mt < 4; mt++) {
            const int r = mt * 16 + (lane & 15);
            const int byte = (r * 256 + ks * 64 + (lane >> 4) * 16) ^ ((r & 7) << 4);
            a[mt] = *(const short8*)(xb + byte);
        }
#pragma unroll
        for (int mt = 0; mt < 4; mt++)
#pragma unroll
            for (int nt = 0; nt < 4; nt++)
                acc[mt][nt] = __builtin_amdgcn_mfma_f32_16x16x32_bf16(
                    a[mt], b[nt][ks], acc[mt][nt], 0, 0, 0);
    }

    // epilogue: D frag col=lane&15, row=(lane>>4)*4+reg (m89-verified)
#pragma unroll
    for (int nt = 0; nt < 4; nt++) {
        const int col = w * 64 + nt * 16 + (lane & 15);
        unsigned short* dst = (col < 128) ? (proj16 + col) : (skip16 + col - 128);
#pragma unroll
        for (int mt = 0; mt < 4; mt++) {
            const int rbase = row0 + mt * 16 + ((lane >> 4) << 2);
            f32x4 v = acc[mt][nt];
#pragma unroll
            for (int reg = 0; reg < 4; reg++) {
                const int row = rbase + reg;
                if (row < N) dst[(size_t)row * HF] = f2bf(v[reg]);
            }
        }
    }
}

// ---------------- per-(node,head) attention score halves + global maxes ----------------
__global__ __launch_bounds__(256) void k_scores(
    const unsigned short* __restrict__ proj16,
    const float* __restrict__ a_src, const float* __restrict__ a_trg,
    float* __restrict__ ssrc, float* __restrict__ strg,
    unsigned int* __restrict__ maxbuf, int N)
{
    __shared__ unsigned int smax[16];
    const int t = threadIdx.x;
    if (t < 16) smax[t] = 0u;
    __syncthreads();
    const int idx = blockIdx.x * 256 + t;      // exact grid: N*8 threads
    const int row = idx >> 3, h = idx & 7;
    const int l = t & 63;

    const uint4 q0 = *(const uint4*)(proj16 + (size_t)row * HF + h * 16);
    const uint4 q1 = *(const uint4*)(proj16 + (size_t)row * HF + h * 16 + 8);
    const float4* as4 = (const float4*)(a_src + h * 16);
    const float4* at4 = (const float4*)(a_trg + h * 16);
    float p[16] = { bf_lo(q0.x), bf_hi(q0.x), bf_lo(q0.y), bf_hi(q0.y),
                    bf_lo(q0.z), bf_hi(q0.z), bf_lo(q0.w), bf_hi(q0.w),
                    bf_lo(q1.x), bf_hi(q1.x), bf_lo(q1.y), bf_hi(q1.y),
                    bf_lo(q1.z), bf_hi(q1.z), bf_lo(q1.w), bf_hi(q1.w) };
    float ps = 0.f, pt = 0.f;
#pragma unroll
    for (int g = 0; g < 4; g++) {
        const float4 A = as4[g], T = at4[g];
        ps += p[g*4+0]*A.x + p[g*4+1]*A.y + p[g*4+2]*A.z + p[g*4+3]*A.w;
        pt += p[g*4+0]*T.x + p[g*4+1]*T.y + p[g*4+2]*T.z + p[g*4+3]*T.w;
    }
    ssrc[idx] = ps;
    strg[idx] = pt;

    float ms = ps, mt_ = pt;
    ms = fmaxf(ms, __shfl_xor(ms, 8));  mt_ = fmaxf(mt_, __shfl_xor(mt_, 8));
    ms = fmaxf(ms, __shfl_xor(ms, 16)); mt_ = fmaxf(mt_, __shfl_xor(mt_, 16));
    ms = fmaxf(ms, __shfl_xor(ms, 32)); mt_ = fmaxf(mt_, __shfl_xor(mt_, 32));
    if (l < 8) {
        atomicMax(&smax[l], enc_f(ms));
        atomicMax(&smax[8 + l], enc_f(mt_));
    }
    __syncthreads();
    if (t < 16) atomicMax(&maxbuf[t], smax[t]);
}

// ---------------- degree histogram ----------------
__global__ __launch_bounds__(256) void k_hist(
    const int* __restrict__ ei, int* __restrict__ offs, int E)
{
    const int e = blockIdx.x * 256 + threadIdx.x;
    if (e < E) atomicAdd(&offs[ei[E + e]], 1);
}

// ---------------- two-level exclusive scan ----------------
__global__ __launch_bounds__(1024) void k_scan_local(
    int* __restrict__ offs, int* __restrict__ bsums, int N)
{
    __shared__ int lds[1024];
    const int t = threadIdx.x;
    const int base = blockIdx.x * 4096 + t * 4;
    int4 v = make_int4(0, 0, 0, 0);
    if (base + 3 < N) v = *(const int4*)(offs + base);
    else {
        if (base + 0 < N) v.x = offs[base + 0];
        if (base + 1 < N) v.y = offs[base + 1];
        if (base + 2 < N) v.z = offs[base + 2];
        if (base + 3 < N) v.w = offs[base + 3];
    }
    const int s = v.x + v.y + v.z + v.w;
    lds[t] = s;
    __syncthreads();
    for (int off = 1; off < 1024; off <<= 1) {
        int u = (t >= off) ? lds[t - off] : 0;
        __syncthreads();
        lds[t] += u;
        __syncthreads();
    }
    if (t == 1023) bsums[blockIdx.x] = lds[1023];
    int run = lds[t] - s;
    int4 w;
    w.x = run; run += v.x;
    w.y = run; run += v.y;
    w.z = run; run += v.z;
    w.w = run;
    if (base + 3 < N) *(int4*)(offs + base) = w;
    else {
        if (base + 0 < N) offs[base + 0] = w.x;
        if (base + 1 < N) offs[base + 1] = w.y;
        if (base + 2 < N) offs[base + 2] = w.z;
        if (base + 3 < N) offs[base + 3] = w.w;
    }
}

__global__ __launch_bounds__(256) void k_scan_bsum(int* __restrict__ bsums, int nb)
{
    __shared__ int lds[256];
    const int t = threadIdx.x;
    const int v = (t < nb) ? bsums[t] : 0;
    lds[t] = v;
    __syncthreads();
    for (int off = 1; off < 256; off <<= 1) {
        int u = (t >= off) ? lds[t - off] : 0;
        __syncthreads();
        lds[t] += u;
        __syncthreads();
    }
    if (t < nb) bsums[t] = lds[t] - v;
}

__global__ __launch_bounds__(1024) void k_scan_add(
    int* __restrict__ offs, const int* __restrict__ bsums, int N)
{
    const int add = bsums[blockIdx.x];
    if (add == 0) return;
    const int base = blockIdx.x * 4096 + threadIdx.x * 4;
    if (base + 3 < N) {
        int4 v = *(int4*)(offs + base);
        v.x += add; v.y += add; v.z += add; v.w += add;
        *(int4*)(offs + base) = v;
    } else {
        for (int i = 0; i < 4; i++) if (base + i < N) offs[base + i] += add;
    }
}

// ---------------- scatter edge srcs into CSR (cursor trick) ----------------
__global__ __launch_bounds__(256) void k_scatter(
    const int* __restrict__ ei, int* __restrict__ offs,
    int* __restrict__ csr_src, int E)
{
    const int e = blockIdx.x * 256 + threadIdx.x;
    if (e >= E) return;
    const int s  = ei[e];
    const int tg = ei[E + e];
    const int pos = atomicAdd(&offs[tg], 1);
    csr_src[pos] = s;
}

// ---------------- gather aggregation: one 64-lane wave per target node ----------------
// lane l: head h=l>>3, feat pair f2=(l&7)*2 -> bf16 pair at proj16[s*128 + l*2].
__global__ __launch_bounds__(256) void k_agg_csr(
    const int* __restrict__ offs, const int* __restrict__ csr_src,
    const float* __restrict__ ssrc, const float* __restrict__ strg,
    const unsigned short* __restrict__ proj16, const unsigned short* __restrict__ skip16,
    const float* __restrict__ bias, const unsigned int* __restrict__ maxbuf,
    float* __restrict__ out, int N)
{
    __shared__ float Msh;
    if (threadIdx.x == 0) {
        float M = -3e38f;
        for (int h = 0; h < 8; h++) M = fmaxf(M, dec_f(maxbuf[h]) + dec_f(maxbuf[8 + h]));
        Msh = M;
    }
    __syncthreads();
    const float M = Msh;
    const int wid = threadIdx.x >> 6;
    const int l   = threadIdx.x & 63;
    const int t   = blockIdx.x * 4 + wid;
    if (t >= N) return;
    const int h = l >> 3;

    const int start = (t == 0) ? 0 : offs[t - 1];
    const int end   = offs[t];
    const float st = strg[(size_t)t * 8 + h];

    float acc0 = 0.f, acc1 = 0.f, den = 0.f;
    int s_next = (start < end) ? csr_src[start] : 0;
    for (int i = start; i < end; i++) {
        const int s = s_next;
        if (i + 1 < end) s_next = csr_src[i + 1];
        float v = ssrc[(size_t)s * 8 + h] + st;
        v = v > 0.f ? v : 0.2f * v;
        const float p = __expf(v - M);
        den += p;
        const unsigned int pv = *(const unsigned int*)(proj16 + (size_t)s * HF + (l << 1));
        acc0 += p * bf_lo(pv);
        acc1 += p * bf_hi(pv);
    }

    const float inv = 1.f / (den + 1e-16f);
    const unsigned int skv = *(const unsigned int*)(skip16 + (size_t)t * HF + (l << 1));
    const float2 bv = *(const float2*)(bias + (l << 1));
    float r0 = acc0 * inv + bf_lo(skv) + bv.x;
    float r1 = acc1 * inv + bf_hi(skv) + bv.y;
    r0 = r0 > 0.f ? r0 : expm1f(r0);
    r1 = r1 > 0.f ? r1 : expm1f(r1);
    *(float2*)(out + (size_t)t * HF + (l << 1)) = make_float2(r0, r1);
}

extern "C" void kernel_launch(void* const* d_in, const int* in_sizes, int n_in,
                              void* d_out, int out_size, void* d_ws, size_t ws_size,
                              hipStream_t stream)
{
    const float* x      = (const float*)d_in[0];
    const int*   ei     = (const int*)d_in[1];
    const float* W_proj = (const float*)d_in[2];
    const float* a_src  = (const float*)d_in[3];
    const float* a_trg  = (const float*)d_in[4];
    const float* W_skip = (const float*)d_in[5];
    const float* bias   = (const float*)d_in[6];
    float* out = (float*)d_out;

    const int N = in_sizes[0] / FIN;
    const int E = in_sizes[1] / 2;

    unsigned short* proj16 = (unsigned short*)d_ws;               // N*128 bf16
    unsigned short* skip16 = proj16 + (size_t)N * HF;             // N*128 bf16
    float* ssrc = (float*)(skip16 + (size_t)N * HF);              // N*8 f32
    float* strg = ssrc + (size_t)N * 8;                           // N*8 f32
    int*   offs = (int*)(strg + (size_t)N * 8);                   // N+1 ints
    unsigned int* maxbuf = (unsigned int*)(offs + (size_t)N + 1); // 16 u32
    int*   bsums = (int*)(maxbuf + 16);                           // 256 ints
    unsigned short* Wb = (unsigned short*)(((uintptr_t)(bsums + 256) + 15) & ~(uintptr_t)15); // 32768 bf16
    int*   csr_src = (int*)(Wb + 32768);                          // E ints

    // zero offs + maxbuf (ws is poisoned 0xAA before every timed launch)
    hipMemsetAsync(offs, 0, ((size_t)N + 1 + 16) * sizeof(int), stream);

    k_prep<<<16, 256, 0, stream>>>(W_proj, W_skip, Wb);
    k_gemm_mfma<<<(N + 63) / 64, 256, 0, stream>>>(x, Wb, proj16, skip16, N);
    k_scores<<<(N * 8) / 256, 256, 0, stream>>>(proj16, a_src, a_trg, ssrc, strg, maxbuf, N);
    k_hist<<<(E + 255) / 256, 256, 0, stream>>>(ei, offs, E);

    const int scan_blocks = (N + 4095) / 4096;
    k_scan_local<<<scan_blocks, 1024, 0, stream>>>(offs, bsums, N);
    k_scan_bsum<<<1, 256, 0, stream>>>(bsums, scan_blocks);
    k_scan_add<<<scan_blocks, 1024, 0, stream>>>(offs, bsums, N);

    k_scatter<<<(E + 255) / 256, 256, 0, stream>>>(ei, offs, csr_src, E);
    k_agg_csr<<<(N + 3) / 4, 256, 0, stream>>>(offs, csr_src, ssrc, strg,
                                               proj16, skip16, bias, maxbuf, out, N);
}

// Round 6
// 457.647 us; speedup vs baseline: 7.7671x; 1.0719x over previous
//
#include <hip/hip_runtime.h>
#include <math.h>

// GAT layer: N nodes, E edges, FIN=128 in-features, H=8 heads, F=16 per head.
// Round-5 pipeline (resubmit — round-5 bench hit GPUAcquisitionTimeout):
//   memset(offs, maxbuf)
//   k_prep     : repack Wp||Wk into MFMA B-frag bf16 layout
//   k_gemm_mfma: proj16/skip16 = bf16(x@W) via 16x16x32 MFMA; epilogue goes
//                through swizzled LDS -> coalesced 16B stores; FUSED score
//                halves (pre-scaled by log2e) + per-head global maxes.
//   k_hist     : offs[trg]++                  (2 edges/thread, int atomics)
//   k_scan_*   : two-level exclusive prefix sum
//   k_scatter  : csr_src[offs[trg]++] = src   (2 edges/thread, cursor trick)
//   k_agg_csr  : per-node wave gathers in-edges (depth-2 pipelined, 32-bit
//                offsets, exp2), writes out = elu(sum/den + skip + bias).

#define HF 128   // H*F
#define FIN 128
#define LOG2E 1.44269504f

typedef __attribute__((ext_vector_type(8))) short short8;   // 8 bf16 (4 VGPR)
typedef __attribute__((ext_vector_type(4))) float f32x4;    // MFMA acc

__device__ __forceinline__ unsigned int enc_f(float f) {
    unsigned int u = __float_as_uint(f);
    return (u & 0x80000000u) ? ~u : (u | 0x80000000u);
}
__device__ __forceinline__ float dec_f(unsigned int e) {
    return (e & 0x80000000u) ? __uint_as_float(e ^ 0x80000000u) : __uint_as_float(~e);
}
__device__ __forceinline__ unsigned short f2bf(float f) {   // RNE f32->bf16
    unsigned int u = __float_as_uint(f);
    return (unsigned short)((u + 0x7FFFu + ((u >> 16) & 1u)) >> 16);
}
__device__ __forceinline__ float bf_lo(unsigned int u) { return __uint_as_float(u << 16); }
__device__ __forceinline__ float bf_hi(unsigned int u) { return __uint_as_float(u & 0xFFFF0000u); }

// ---------------- W repack into MFMA B-frag layout ----------------
// Frag fi=(ct*4+ks): lane l, elem j <- W'[k=ks*32+(l>>4)*8+j][c=ct*16+(l&15)],
// W' = [Wp | Wk] (256 cols). Output: Wb[fi*512 + l*8 + j] bf16.
__global__ __launch_bounds__(256) void k_prep(
    const float* __restrict__ Wp, const float* __restrict__ Wk,
    unsigned short* __restrict__ Wb)
{
    const int ct = blockIdx.x;          // 0..15
    const int t = threadIdx.x;
    const int ks = t >> 6, lane = t & 63;
    const int k0 = ks * 32 + (lane >> 4) * 8;
    const int c  = ct * 16 + (lane & 15);
    const float* W = (c < 128) ? (Wp + c) : (Wk + c - 128);
    unsigned short v[8];
#pragma unroll
    for (int j = 0; j < 8; j++) v[j] = f2bf(W[(k0 + j) * HF]);
    uint4 q;
    q.x = v[0] | ((unsigned int)v[1] << 16);
    q.y = v[2] | ((unsigned int)v[3] << 16);
    q.z = v[4] | ((unsigned int)v[5] << 16);
    q.w = v[6] | ((unsigned int)v[7] << 16);
    *(uint4*)(Wb + ((size_t)(ct * 4 + ks) * 64 + lane) * 8) = q;
}

// ---------------- MFMA GEMM + LDS-bounced epilogue + fused scores ----------------
// 4 waves/block; wave w owns cols w*64..w*64+63 of [proj|skip].
// ob swizzle: lds_col(row,c) = c ^ (((row>>2)&3)<<4)  (spreads the 4 lane
// row-groups across disjoint 8-bank sets on frag writes).
__global__ __launch_bounds__(256) void k_gemm_mfma(
    const float* __restrict__ x, const unsigned short* __restrict__ Wb,
    const float* __restrict__ av_src, const float* __restrict__ av_trg,
    unsigned short* __restrict__ proj16, unsigned short* __restrict__ skip16,
    float* __restrict__ ssrc, float* __restrict__ strg,
    unsigned int* __restrict__ maxbuf, int N)
{
    __shared__ unsigned short xs[64 * FIN];    // 16 KB, swizzled bf16 x-tile
    __shared__ unsigned short ob[64][256];     // 32 KB, swizzled bf16 out-tile
    __shared__ unsigned int smax[16];
    char* xb = (char*)xs;
    const int t = threadIdx.x;
    const int w = t >> 6, lane = t & 63;
    const int row0 = blockIdx.x * 64;
    if (t < 16) smax[t] = 0u;

    // B-frags in registers (L2-hot)
    short8 b[4][4];
    {
        const short8* wb8 = (const short8*)Wb;
#pragma unroll
        for (int nt = 0; nt < 4; nt++)
#pragma unroll
            for (int ks = 0; ks < 4; ks++)
                b[nt][ks] = wb8[(size_t)(w * 16 + nt * 4 + ks) * 64 + lane];
    }

    // stage x tile -> bf16 LDS (swizzled byte ^= (row&7)<<4)
    {
        const float4* xg = (const float4*)(x + (size_t)row0 * FIN);
#pragma unroll
        for (int it = 0; it < 8; it++) {
            const int i = t + it * 256;
            const int row = i >> 5, c4 = i & 31;
            float4 v = make_float4(0.f, 0.f, 0.f, 0.f);
            if (row0 + row < N) v = xg[i];
            ushort4 pk;
            pk.x = f2bf(v.x); pk.y = f2bf(v.y); pk.z = f2bf(v.z); pk.w = f2bf(v.w);
            const int byte = (row * 256 + c4 * 8) ^ ((row & 7) << 4);
            *(ushort4*)(xb + byte) = pk;
        }
    }
    __syncthreads();

    f32x4 acc[4][4];
#pragma unroll
    for (int mt = 0; mt < 4; mt++)
#pragma unroll
        for (int nt = 0; nt < 4; nt++)
            acc[mt][nt] = (f32x4){0.f, 0.f, 0.f, 0.f};

#pragma unroll
    for (int ks = 0; ks < 4; ks++) {
        short8 a[4];
#pragma unroll
        for (int mt = 0; mt < 4; mt++) {
            const int r = mt * 16 + (lane & 15);
            const int byte = (r * 256 + ks * 64 + (lane >> 4) * 16) ^ ((r & 7) << 4);
            a[mt] = *(const short8*)(xb + byte);
        }
#pragma unroll
        for (int mt = 0; mt < 4; mt++)
#pragma unroll
            for (int nt = 0; nt < 4; nt++)
                acc[mt][nt] = __builtin_amdgcn_mfma_f32_16x16x32_bf16(
                    a[mt], b[nt][ks], acc[mt][nt], 0, 0, 0);
    }

    // ---- D frags -> ob (bf16, swizzled). frag: col=lane&15, row=(lane>>4)*4+reg
    const int g = lane >> 4;
#pragma unroll
    for (int nt = 0; nt < 4; nt++) {
        const int csw = (w * 64 + nt * 16 + (lane & 15)) ^ (g << 4);
#pragma unroll
        for (int mt = 0; mt < 4; mt++) {
            const int rbase = mt * 16 + (g << 2);
            f32x4 v = acc[mt][nt];
#pragma unroll
            for (int reg = 0; reg < 4; reg++)
                ob[rbase + reg][csw] = f2bf(v[reg]);
        }
    }
    __syncthreads();

    // ---- coalesced 16B stores
#pragma unroll
    for (int it = 0; it < 8; it++) {
        const int i = t + it * 256;
        const int row = i >> 5, seg = i & 31;
        const int c0 = (seg * 8) ^ (((row >> 2) & 3) << 4);
        const uint4 q = *(const uint4*)&ob[row][c0];
        const int grow = row0 + row;
        if (grow < N) {
            if (seg < 16) *(uint4*)(proj16 + (size_t)grow * HF + seg * 8) = q;
            else          *(uint4*)(skip16 + (size_t)grow * HF + (seg - 16) * 8) = q;
        }
    }

    // ---- fused scores: 512 (row,head) tasks, 2 per thread; pre-scaled by log2e
#pragma unroll
    for (int j = 0; j < 2; j++) {
        const int id = (t << 1) | j;
        const int row = id >> 3, h = id & 7;
        const int cb = (h * 16) ^ (((row >> 2) & 3) << 4);
        const unsigned int* pq = (const unsigned int*)&ob[row][cb];
        float ps = 0.f, pt = 0.f;
#pragma unroll
        for (int gg = 0; gg < 8; gg++) {
            const unsigned int q = pq[gg];
            const float lo = bf_lo(q), hi = bf_hi(q);
            const float2 A = *(const float2*)(av_src + h * 16 + gg * 2);
            const float2 T = *(const float2*)(av_trg + h * 16 + gg * 2);
            ps += lo * A.x + hi * A.y;
            pt += lo * T.x + hi * T.y;
        }
        ps *= LOG2E; pt *= LOG2E;
        const int grow = row0 + row;
        if (grow < N) {
            ssrc[(size_t)grow * 8 + h] = ps;
            strg[(size_t)grow * 8 + h] = pt;
            atomicMax(&smax[h], enc_f(ps));
            atomicMax(&smax[8 + h], enc_f(pt));
        }
    }
    __syncthreads();
    if (t < 16) atomicMax(&maxbuf[t], smax[t]);
}

// ---------------- degree histogram (2 edges/thread) ----------------
__global__ __launch_bounds__(256) void k_hist(
    const int* __restrict__ ei, int* __restrict__ offs, int E)
{
    const int e = (blockIdx.x * 256 + threadIdx.x) * 2;
    if (e + 1 < E) {
        const int2 tg = *(const int2*)(ei + E + e);
        atomicAdd(&offs[tg.x], 1);
        atomicAdd(&offs[tg.y], 1);
    } else if (e < E) {
        atomicAdd(&offs[ei[E + e]], 1);
    }
}

// ---------------- two-level exclusive scan ----------------
__global__ __launch_bounds__(1024) void k_scan_local(
    int* __restrict__ offs, int* __restrict__ bsums, int N)
{
    __shared__ int lds[1024];
    const int t = threadIdx.x;
    const int base = blockIdx.x * 4096 + t * 4;
    int4 v = make_int4(0, 0, 0, 0);
    if (base + 3 < N) v = *(const int4*)(offs + base);
    else {
        if (base + 0 < N) v.x = offs[base + 0];
        if (base + 1 < N) v.y = offs[base + 1];
        if (base + 2 < N) v.z = offs[base + 2];
        if (base + 3 < N) v.w = offs[base + 3];
    }
    const int s = v.x + v.y + v.z + v.w;
    lds[t] = s;
    __syncthreads();
    for (int off = 1; off < 1024; off <<= 1) {
        int u = (t >= off) ? lds[t - off] : 0;
        __syncthreads();
        lds[t] += u;
        __syncthreads();
    }
    if (t == 1023) bsums[blockIdx.x] = lds[1023];
    int run = lds[t] - s;
    int4 w;
    w.x = run; run += v.x;
    w.y = run; run += v.y;
    w.z = run; run += v.z;
    w.w = run;
    if (base + 3 < N) *(int4*)(offs + base) = w;
    else {
        if (base + 0 < N) offs[base + 0] = w.x;
        if (base + 1 < N) offs[base + 1] = w.y;
        if (base + 2 < N) offs[base + 2] = w.z;
        if (base + 3 < N) offs[base + 3] = w.w;
    }
}

__global__ __launch_bounds__(256) void k_scan_bsum(int* __restrict__ bsums, int nb)
{
    __shared__ int lds[256];
    const int t = threadIdx.x;
    const int v = (t < nb) ? bsums[t] : 0;
    lds[t] = v;
    __syncthreads();
    for (int off = 1; off < 256; off <<= 1) {
        int u = (t >= off) ? lds[t - off] : 0;
        __syncthreads();
        lds[t] += u;
        __syncthreads();
    }
    if (t < nb) bsums[t] = lds[t] - v;
}

__global__ __launch_bounds__(1024) void k_scan_add(
    int* __restrict__ offs, const int* __restrict__ bsums, int N)
{
    const int add = bsums[blockIdx.x];
    if (add == 0) return;
    const int base = blockIdx.x * 4096 + threadIdx.x * 4;
    if (base + 3 < N) {
        int4 v = *(int4*)(offs + base);
        v.x += add; v.y += add; v.z += add; v.w += add;
        *(int4*)(offs + base) = v;
    } else {
        for (int i = 0; i < 4; i++) if (base + i < N) offs[base + i] += add;
    }
}

// ---------------- scatter edge srcs into CSR (2 edges/thread, cursor trick) ----------------
__global__ __launch_bounds__(256) void k_scatter(
    const int* __restrict__ ei, int* __restrict__ offs,
    int* __restrict__ csr_src, int E)
{
    const int e = (blockIdx.x * 256 + threadIdx.x) * 2;
    if (e + 1 < E) {
        const int2 s  = *(const int2*)(ei + e);
        const int2 tg = *(const int2*)(ei + E + e);
        const int p0 = atomicAdd(&offs[tg.x], 1);
        csr_src[p0] = s.x;
        const int p1 = atomicAdd(&offs[tg.y], 1);
        csr_src[p1] = s.y;
    } else if (e < E) {
        const int pos = atomicAdd(&offs[ei[E + e]], 1);
        csr_src[pos] = ei[e];
    }
}

// ---------------- gather aggregation: one 64-lane wave per target node ----------------
// lane l: head h=l>>3, u32 = bf16 pair at proj16[s*128 + l*2]. Scores are
// pre-scaled by log2e, so p = exp2(lrelu(ss+st) - M).
__global__ __launch_bounds__(256) void k_agg_csr(
    const int* __restrict__ offs, const int* __restrict__ csr_src,
    const float* __restrict__ ssrc, const float* __restrict__ strg,
    const unsigned short* __restrict__ proj16, const unsigned short* __restrict__ skip16,
    const float* __restrict__ bias, const unsigned int* __restrict__ maxbuf,
    float* __restrict__ out, int N)
{
    __shared__ float Msh;
    if (threadIdx.x == 0) {
        float M = -3e38f;
        for (int h = 0; h < 8; h++) M = fmaxf(M, dec_f(maxbuf[h]) + dec_f(maxbuf[8 + h]));
        Msh = M;
    }
    __syncthreads();
    const float M = Msh;
    const int wid = threadIdx.x >> 6;
    const int l   = threadIdx.x & 63;
    const int t   = blockIdx.x * 4 + wid;
    if (t >= N) return;
    const int h = l >> 3;

    const int start = (t == 0) ? 0 : offs[t - 1];
    const int end   = offs[t];
    const int n     = end - start;
    const float st  = strg[(unsigned)t * 8u + h];
    const unsigned int* pu = (const unsigned int*)proj16;

    float acc0 = 0.f, acc1 = 0.f, den = 0.f;
    int s1 = 0; unsigned pv0 = 0; float ss0 = 0.f;
    if (n > 0) {
        const int s0 = csr_src[start];
        s1  = (n > 1) ? csr_src[start + 1] : s0;
        pv0 = pu[(unsigned)s0 * 64u + l];
        ss0 = ssrc[(unsigned)s0 * 8u + h];
    }
    for (int i = start; i < end; ++i) {
        const int s2 = (i + 2 < end) ? csr_src[i + 2] : s1;
        const unsigned pv1 = pu[(unsigned)s1 * 64u + l];
        const float ss1 = ssrc[(unsigned)s1 * 8u + h];
        float z = ss0 + st;
        z = fmaxf(z, 0.2f * z);                       // lrelu (commutes with +scale)
        const float p = __builtin_amdgcn_exp2f(z - M);
        den += p;
        acc0 = fmaf(p, bf_lo(pv0), acc0);
        acc1 = fmaf(p, bf_hi(pv0), acc1);
        pv0 = pv1; ss0 = ss1; s1 = s2;
    }

    const float inv = 1.f / (den + 1e-16f);
    const unsigned skv = ((const unsigned int*)skip16)[(unsigned)t * 64u + l];
    const float2 bv = *(const float2*)(bias + (l << 1));
    float r0 = fmaf(acc0, inv, bf_lo(skv) + bv.x);
    float r1 = fmaf(acc1, inv, bf_hi(skv) + bv.y);
    r0 = r0 > 0.f ? r0 : expm1f(r0);
    r1 = r1 > 0.f ? r1 : expm1f(r1);
    *(float2*)(out + (size_t)t * HF + (l << 1)) = make_float2(r0, r1);
}

extern "C" void kernel_launch(void* const* d_in, const int* in_sizes, int n_in,
                              void* d_out, int out_size, void* d_ws, size_t ws_size,
                              hipStream_t stream)
{
    const float* x      = (const float*)d_in[0];
    const int*   ei     = (const int*)d_in[1];
    const float* W_proj = (const float*)d_in[2];
    const float* a_src  = (const float*)d_in[3];
    const float* a_trg  = (const float*)d_in[4];
    const float* W_skip = (const float*)d_in[5];
    const float* bias   = (const float*)d_in[6];
    float* out = (float*)d_out;

    const int N = in_sizes[0] / FIN;
    const int E = in_sizes[1] / 2;

    unsigned short* proj16 = (unsigned short*)d_ws;               // N*128 bf16
    unsigned short* skip16 = proj16 + (size_t)N * HF;             // N*128 bf16
    float* ssrc = (float*)(skip16 + (size_t)N * HF);              // N*8 f32
    float* strg = ssrc + (size_t)N * 8;                           // N*8 f32
    int*   offs = (int*)(strg + (size_t)N * 8);                   // N+1 ints
    unsigned int* maxbuf = (unsigned int*)(offs + (size_t)N + 1); // 16 u32
    int*   bsums = (int*)(maxbuf + 16);                           // 256 ints
    unsigned short* Wb = (unsigned short*)(((uintptr_t)(bsums + 256) + 15) & ~(uintptr_t)15); // 32768 bf16
    int*   csr_src = (int*)(Wb + 32768);                          // E ints

    // zero offs + maxbuf (ws is poisoned 0xAA before every timed launch)
    hipMemsetAsync(offs, 0, ((size_t)N + 1 + 16) * sizeof(int), stream);

    k_prep<<<16, 256, 0, stream>>>(W_proj, W_skip, Wb);
    k_gemm_mfma<<<(N + 63) / 64, 256, 0, stream>>>(x, Wb, a_src, a_trg,
                                                   proj16, skip16, ssrc, strg, maxbuf, N);
    k_hist<<<(E / 2 + 255) / 256, 256, 0, stream>>>(ei, offs, E);

    const int scan_blocks = (N + 4095) / 4096;
    k_scan_local<<<scan_blocks, 1024, 0, stream>>>(offs, bsums, N);
    k_scan_bsum<<<1, 256, 0, stream>>>(bsums, scan_blocks);
    k_scan_add<<<scan_blocks, 1024, 0, stream>>>(offs, bsums, N);

    k_scatter<<<(E / 2 + 255) / 256, 256, 0, stream>>>(ei, offs, csr_src, E);
    k_agg_csr<<<(N + 3) / 4, 256, 0, stream>>>(offs, csr_src, ssrc, strg,
                                               proj16, skip16, bias, maxbuf, out, N);
}